// Round 1
// baseline (353.215 us; speedup 1.0000x reference)
//
#include <hip/hip_runtime.h>
#include <math.h>

#define LSEQ   2048
#define DMODEL 256
#define NHALF  32
#define TMAX   1024                 // h-series truncation (|A|^1024 ~ e^-51)
#define KPAD   16                   // zero-pad rows each side of kT
#define KROWS  (LSEQ + 2*KPAD)      // 2080
#define TT     16                   // t-tile per block

// Stage 1: build transposed, padded conv kernel kT[jp][d], jp = j + KPAD.
// k[d,t] = Re h[t]  -  (1/L) * sum_{tau: t-tau odd} cot(pi*(t-tau)/(2L)) * Im h[tau]
// h[tau] = sum_n C_n * A_n^tau,  A_n = exp((-exp(A_real)+i*A_imag)*dt)
__global__ __launch_bounds__(256) void s4d_build_k(
    const float* __restrict__ A_real, const float* __restrict__ A_imag,
    const float* __restrict__ C_real, const float* __restrict__ C_imag,
    float* __restrict__ kT)
{
    __shared__ float hRe[TMAX], hIm[TMAX], ct[LSEQ], prm[4][NHALF];
    const int tid = threadIdx.x;
    const int d   = blockIdx.x;

    if (tid < NHALF) {
        prm[0][tid] = A_real[d*NHALF + tid];
        prm[1][tid] = A_imag[d*NHALF + tid];
        prm[2][tid] = C_real[d*NHALF + tid];
        prm[3][tid] = C_imag[d*NHALF + tid];
    }
    // cot table: ct[i] = cot(pi*(2i+1)/(2*2L)), i = 0..2047  (odd deltas mod 4096)
    #pragma unroll
    for (int r = 0; r < LSEQ/256; ++r) {
        int i = tid + 256*r;
        float ang = (float)(M_PI/(2.0*(double)LSEQ)) * (float)(2*i + 1);
        float sv, cv;
        sincosf(ang, &sv, &cv);
        ct[i] = cv / sv;
    }
    __syncthreads();

    // h[tau], tau = 0..TMAX-1
    for (int r = 0; r < TMAX/256; ++r) {
        int tau = tid + 256*r;
        float aR = 0.f, aI = 0.f;
        for (int n = 0; n < NHALF; ++n) {
            float lr  = -expf(prm[0][n]) * 0.1f;          // log|A| per step
            float amp = expf(lr * (float)tau);            // |A|^tau
            double ph = (double)prm[1][n] * 0.1 * (double)tau;  // phase, reduced in f64
            ph -= floor(ph * (1.0/(2.0*M_PI))) * (2.0*M_PI);
            float s, c;
            sincosf((float)ph, &s, &c);
            float cr = prm[2][n], ci = prm[3][n];
            aR = fmaf(amp, cr*c - ci*s, aR);
            aI = fmaf(amp, cr*s + ci*c, aI);
        }
        hRe[tau] = aR; hIm[tau] = aI;
    }
    __syncthreads();

    // k[t], t = 0..LSEQ-1 (8 t's per thread, all same parity as tid)
    float base[8], hsum[8];
    #pragma unroll
    for (int r = 0; r < 8; ++r) {
        base[r] = (r < 4) ? hRe[tid + 256*r] : 0.f;   // t<TMAX <=> r<4
        hsum[r] = 0.f;
    }
    const int tau0 = (tid & 1) ^ 1;   // opposite parity -> odd delta
    for (int tau = tau0; tau < TMAX; tau += 2) {
        float him = hIm[tau];
        #pragma unroll
        for (int r = 0; r < 8; ++r) {
            int idx = ((tid + 256*r - tau) & (2*LSEQ - 1)) >> 1;
            hsum[r] = fmaf(ct[idx], him, hsum[r]);
        }
    }
    #pragma unroll
    for (int r = 0; r < 8; ++r) {
        int t = tid + 256*r;
        kT[(t + KPAD)*DMODEL + d] = base[r] - hsum[r] * (1.0f/(float)LSEQ);
    }
    // zero the pad rows (this block's column only -> deterministic, no races)
    if (tid < 2*KPAD) {
        int row = (tid < KPAD) ? tid : (LSEQ + KPAD + (tid - KPAD));
        kT[row*DMODEL + d] = 0.f;
    }
}

// Stage 2: y[b,t,d] = D[d] + sum_m u[b,m,d] * kT[m - t + 1023 + KPAD][d]
// block = (t-tile of TT, b), thread = d. k window slides in registers.
__global__ __launch_bounds__(256) void s4d_conv(
    const float* __restrict__ u, const float* __restrict__ Dvec,
    const float* __restrict__ kT, float* __restrict__ out)
{
    const int d  = threadIdx.x;
    const int t0 = blockIdx.x * TT;
    const int b  = blockIdx.y;

    float dv = Dvec[d];
    float acc[TT];
    #pragma unroll
    for (int i = 0; i < TT; ++i) acc[i] = dv;

    const float* ub   = u + (size_t)b * LSEQ * DMODEL + d;
    const float* kcol = kT + d;

    int mstart = t0 - 1024; if (mstart < 0) mstart = 0;        // multiple of 16
    int mend   = t0 + 1040; if (mend > LSEQ) mend = LSEQ;      // multiple of 16

    // jp = m - t + 1024 + (mm - tt + 15); window rows jpb .. jpb+30
    float kreg[31];
    {
        int jpb = mstart - t0 + 1024;
        #pragma unroll
        for (int r = 0; r < 31; ++r) kreg[r] = kcol[(jpb + r)*DMODEL];
    }

    for (int m0 = mstart; m0 < mend; m0 += TT) {
        float ureg[TT];
        #pragma unroll
        for (int mm = 0; mm < TT; ++mm) ureg[mm] = ub[(m0 + mm)*DMODEL];

        float knew[TT];
        if (m0 + TT < mend) {                 // prefetch next window's 16 new rows
            int jnb = m0 - t0 + 1024 + 31;
            #pragma unroll
            for (int r = 0; r < TT; ++r) knew[r] = kcol[(jnb + r)*DMODEL];
        } else {
            #pragma unroll
            for (int r = 0; r < TT; ++r) knew[r] = 0.f;
        }

        #pragma unroll
        for (int mm = 0; mm < TT; ++mm)
            #pragma unroll
            for (int tt = 0; tt < TT; ++tt)
                acc[tt] = fmaf(ureg[mm], kreg[mm - tt + 15], acc[tt]);

        #pragma unroll
        for (int r = 0; r < 15; ++r) kreg[r] = kreg[r + 16];
        #pragma unroll
        for (int r = 0; r < 16; ++r) kreg[15 + r] = knew[r];
    }

    float* ob = out + ((size_t)b * LSEQ + t0) * DMODEL + d;
    #pragma unroll
    for (int tt = 0; tt < TT; ++tt) ob[tt*DMODEL] = acc[tt];
}

extern "C" void kernel_launch(void* const* d_in, const int* in_sizes, int n_in,
                              void* d_out, int out_size, void* d_ws, size_t ws_size,
                              hipStream_t stream)
{
    const float* u  = (const float*)d_in[0];
    const float* Ar = (const float*)d_in[1];
    const float* Ai = (const float*)d_in[2];
    const float* Cr = (const float*)d_in[3];
    const float* Ci = (const float*)d_in[4];
    const float* Dv = (const float*)d_in[5];
    float* kT  = (float*)d_ws;                   // KROWS*DMODEL*4 = 2.13 MB
    float* out = (float*)d_out;

    int B = in_sizes[0] / (LSEQ * DMODEL);       // 8

    s4d_build_k<<<DMODEL, 256, 0, stream>>>(Ar, Ai, Cr, Ci, kT);
    s4d_conv<<<dim3(LSEQ/TT, B), 256, 0, stream>>>(u, Dv, kT, out);
}

// Round 2
// 107.461 us; speedup vs baseline: 3.2869x; 3.2869x over previous
//
#include <hip/hip_runtime.h>
#include <hip/hip_bf16.h>
#include <math.h>

#define LSEQ   2048
#define DMODEL 256
#define NHALF  32
#define TMAX   1024
#define KPAD   16
#define KROWS  (LSEQ + 2*KPAD)
#define TT     16

typedef __attribute__((ext_vector_type(8))) short short8;
typedef __attribute__((ext_vector_type(4))) float f32x4;
typedef __attribute__((ext_vector_type(4))) unsigned int u32x4;

// ---- MFMA-path geometry
#define UB_ROWS   8
#define UB_STR    2056                   // bf16 per row (pad 8 for banks)
#define UB_SHORTS (UB_ROWS*UB_STR)       // 16448
#define UB_BYTES  (UB_SHORTS*2)          // 32896
#define KB_LEN    4352                   // padded taps (+1024 lead, +tail)
#define KB_SHORTS (2*KB_LEN)             // two parity-shifted copies
#define KB_BYTES  (KB_SHORTS*2)          // 17408
#define SM_TOTAL  (UB_BYTES + KB_BYTES)  // 50304 B LDS
#define UIMG_SHORTS ((size_t)DMODEL*UB_SHORTS)
#define KB2G_SHORTS ((size_t)DMODEL*KB_SHORTS)
#define WS_NEED   ((UIMG_SHORTS + KB2G_SHORTS)*2)

// ============================================================ stage 0:
// u [B][L][D] f32  ->  uimg [d][b][m] bf16 (row stride UB_STR)
__global__ __launch_bounds__(256) void s4d_utr(const float* __restrict__ u,
                                               unsigned short* __restrict__ uimg)
{
    __shared__ unsigned short tr[DMODEL][66];   // 64 m + pad2
    const int tid = threadIdx.x;
    const int m0  = blockIdx.x * 64;
    const int b   = blockIdx.y;

    const int mmBase = tid >> 6;          // 0..3
    const int d4     = (tid & 63) * 4;
    for (int it = 0; it < 16; ++it) {
        int mm = it*4 + mmBase;
        const float* src = u + ((size_t)b*LSEQ + m0 + mm)*DMODEL + d4;
        f32x4 v = *(const f32x4*)src;
        #pragma unroll
        for (int j = 0; j < 4; ++j) {
            __hip_bfloat16 hb = __float2bfloat16(v[j]);
            tr[d4+j][mm] = *(unsigned short*)&hb;
        }
    }
    __syncthreads();
    {
        const int d = tid;
        unsigned wbuf[32];
        #pragma unroll
        for (int m2 = 0; m2 < 32; ++m2)
            wbuf[m2] = *(const unsigned*)&tr[d][2*m2];
        unsigned short* gp = uimg + (size_t)d*UB_SHORTS + (size_t)b*UB_STR + m0;
        #pragma unroll
        for (int c = 0; c < 8; ++c) {
            u32x4 w = { wbuf[4*c], wbuf[4*c+1], wbuf[4*c+2], wbuf[4*c+3] };
            *(u32x4*)(gp + c*8) = w;
        }
    }
}

// ============================================================ stage 1 (new):
// build k (f32, exact same math as verified R1) then write two parity-shifted
// zero-padded bf16 copies: kb2g[d][s][x] = bf16(k[x + s - 1024]) (0 outside)
__global__ __launch_bounds__(512) void s4d_build_kb(
    const float* __restrict__ A_real, const float* __restrict__ A_imag,
    const float* __restrict__ C_real, const float* __restrict__ C_imag,
    unsigned short* __restrict__ kb2g)
{
    __shared__ float hRe[TMAX], hIm[TMAX], ct[LSEQ], kF[LSEQ], prm[4][NHALF];
    const int tid = threadIdx.x;
    const int d   = blockIdx.x;

    if (tid < NHALF) {
        prm[0][tid] = A_real[d*NHALF + tid];
        prm[1][tid] = A_imag[d*NHALF + tid];
        prm[2][tid] = C_real[d*NHALF + tid];
        prm[3][tid] = C_imag[d*NHALF + tid];
    }
    for (int i = tid; i < LSEQ; i += 512) {
        float ang = (float)(M_PI/(2.0*(double)LSEQ)) * (float)(2*i + 1);
        float sv, cv; sincosf(ang, &sv, &cv);
        ct[i] = cv / sv;
    }
    __syncthreads();

    for (int tau = tid; tau < TMAX; tau += 512) {
        float aR = 0.f, aI = 0.f;
        for (int n = 0; n < NHALF; ++n) {
            float lr  = -expf(prm[0][n]) * 0.1f;
            float amp = expf(lr * (float)tau);
            double ph = (double)prm[1][n] * 0.1 * (double)tau;
            ph -= floor(ph * (1.0/(2.0*M_PI))) * (2.0*M_PI);
            float s, c; sincosf((float)ph, &s, &c);
            float cr = prm[2][n], ci = prm[3][n];
            aR = fmaf(amp, cr*c - ci*s, aR);
            aI = fmaf(amp, cr*s + ci*c, aI);
        }
        hRe[tau] = aR; hIm[tau] = aI;
    }
    __syncthreads();

    {
        float hs[4] = {0.f, 0.f, 0.f, 0.f};
        const int tau0 = (tid & 1) ^ 1;
        for (int tau = tau0; tau < TMAX; tau += 2) {
            float him = hIm[tau];
            #pragma unroll
            for (int r = 0; r < 4; ++r) {
                int idx = ((tid + 512*r - tau) & (2*LSEQ - 1)) >> 1;
                hs[r] = fmaf(ct[idx], him, hs[r]);
            }
        }
        #pragma unroll
        for (int r = 0; r < 4; ++r) {
            int t = tid + 512*r;
            float base = (t < TMAX) ? hRe[t] : 0.f;
            kF[t] = base - hs[r] * (1.0f/(float)LSEQ);
        }
    }
    __syncthreads();

    unsigned short* row = kb2g + (size_t)d*KB_SHORTS;
    for (int x = tid; x < KB_LEN; x += 512) {
        #pragma unroll
        for (int s = 0; s < 2; ++s) {
            int j = x + s - 1024;
            float v = (j >= 0 && j < LSEQ) ? kF[j] : 0.f;
            __hip_bfloat16 hb = __float2bfloat16(v);
            row[s*KB_LEN + x] = *(unsigned short*)&hb;
        }
    }
}

// ============================================================ stage 2:
// per-d Toeplitz GEMM via mfma_f32_16x16x32_bf16.
__device__ __forceinline__ short8 loadA4(const unsigned char* sm, int addr) {
    unsigned a0 = *(const unsigned*)(sm + addr);
    unsigned a1 = *(const unsigned*)(sm + addr + 4);
    unsigned a2 = *(const unsigned*)(sm + addr + 8);
    unsigned a3 = *(const unsigned*)(sm + addr + 12);
    u32x4 v = {a0, a1, a2, a3};
    return __builtin_bit_cast(short8, v);
}
__device__ __forceinline__ short8 loadB16(const unsigned char* sm, int addr) {
    return *(const short8*)(sm + addr);
}
#define MF(a, b, c) __builtin_amdgcn_mfma_f32_16x16x32_bf16((a), (b), (c), 0, 0, 0)

__global__ __launch_bounds__(512, 2) void s4d_mfma(
    const unsigned short* __restrict__ uimg, const unsigned short* __restrict__ kb2g,
    const float* __restrict__ Dvec, float* __restrict__ out)
{
    __shared__ __align__(16) unsigned char sm[SM_TOTAL];
    const int tid = threadIdx.x;
    const int Bk  = blockIdx.x;
    const int d   = ((Bk & 7) << 5) | (Bk >> 3);     // XCD-swizzle: 32 consecutive d per XCD

    // ---- stage LDS (prologue; plain global->reg->ds)
    {
        const u32x4* gu = (const u32x4*)(uimg + (size_t)d*UB_SHORTS);
        u32x4* lu = (u32x4*)sm;
        for (int i = tid; i < UB_SHORTS/8; i += 512) lu[i] = gu[i];
        const u32x4* gk = (const u32x4*)(kb2g + (size_t)d*KB_SHORTS);
        u32x4* lk = (u32x4*)(sm + UB_BYTES);
        for (int i = tid; i < KB_SHORTS/8; i += 512) lk[i] = gk[i];
    }
    __syncthreads();

    const int lane = tid & 63, wv = tid >> 6;
    const int h    = lane >> 4;          // k-chunk id (0..3)
    const int col  = lane & 15;          // A-row / B-col / C-col
    const int t0w  = wv << 8;            // wave's t base (256 rows)

    // A addressing: taps x0 = 2047 + m0 - t0w - 16*tt + 8h - i; copy s=(i+1)&1
    const int s     = (col + 1) & 1;
    const int laneC = UB_BYTES + s*(KB_LEN*2) - 2*s + 2*((h << 3) - col);
    const int baseA = laneC + 2*(2047 - t0w);            // + 2*m0 - 32*tt
    const int laneB = (col & 7)*(UB_STR*2) + (h << 4);   // + 2*m0

    const float dv = Dvec[d];
    f32x4 acc[16];
    #pragma unroll
    for (int tt = 0; tt < 16; ++tt) acc[tt] = (f32x4){dv, dv, dv, dv};

    short8 A[16], Bb[2];
    #pragma unroll
    for (int tt = 0; tt < 16; ++tt) A[tt] = loadA4(sm, baseA - 32*tt);
    Bb[0] = loadB16(sm, laneB);

    int aA = baseA + 64;       // prefetch addr: frag(tt=0, m0+32)
    int aB = laneB + 64;

    for (int Q = 0; Q < 8; ++Q) {
        #pragma unroll
        for (int p = 0; p < 8; ++p) {
            const short8 bcur = Bb[p & 1];
            // slots (14-2p)&15 / (15-2p)&15 are read by tt=14/15 then retired
            acc[14] = MF(A[(14 - 2*p) & 15], bcur, acc[14]);
            acc[15] = MF(A[(15 - 2*p) & 15], bcur, acc[15]);
            A[(14 - 2*p) & 15] = loadA4(sm, aA);         // frag(0, m0+32)
            A[(15 - 2*p) & 15] = loadA4(sm, aA - 32);    // frag(1, m0+32)
            Bb[(p + 1) & 1]    = loadB16(sm, aB);
            aA += 64; aB += 64;
            #pragma unroll
            for (int tt = 2; tt < 14; ++tt)
                acc[tt] = MF(A[(tt - 2*p) & 15], bcur, acc[tt]);
            acc[0] = MF(A[(0 - 2*p) & 15], bcur, acc[0]);
            acc[1] = MF(A[(1 - 2*p) & 15], bcur, acc[1]);
        }
    }

    // ---- epilogue: C[row][col]: row = 4h + r (t within tile), col = batch
    if (col < 8) {
        float* ob = out + (size_t)col*LSEQ*DMODEL + d;
        #pragma unroll
        for (int tt = 0; tt < 16; ++tt) {
            int trow = t0w + tt*16 + h*4;
            float* o = ob + (size_t)trow*DMODEL;
            o[0*DMODEL] = acc[tt][0];
            o[1*DMODEL] = acc[tt][1];
            o[2*DMODEL] = acc[tt][2];
            o[3*DMODEL] = acc[tt][3];
        }
    }
}

// ============================================================ fallback (R1, verified)
__global__ __launch_bounds__(256) void s4d_build_k(
    const float* __restrict__ A_real, const float* __restrict__ A_imag,
    const float* __restrict__ C_real, const float* __restrict__ C_imag,
    float* __restrict__ kT)
{
    __shared__ float hRe[TMAX], hIm[TMAX], ct[LSEQ], prm[4][NHALF];
    const int tid = threadIdx.x;
    const int d   = blockIdx.x;
    if (tid < NHALF) {
        prm[0][tid] = A_real[d*NHALF + tid];
        prm[1][tid] = A_imag[d*NHALF + tid];
        prm[2][tid] = C_real[d*NHALF + tid];
        prm[3][tid] = C_imag[d*NHALF + tid];
    }
    #pragma unroll
    for (int r = 0; r < LSEQ/256; ++r) {
        int i = tid + 256*r;
        float ang = (float)(M_PI/(2.0*(double)LSEQ)) * (float)(2*i + 1);
        float sv, cv; sincosf(ang, &sv, &cv);
        ct[i] = cv / sv;
    }
    __syncthreads();
    for (int r = 0; r < TMAX/256; ++r) {
        int tau = tid + 256*r;
        float aR = 0.f, aI = 0.f;
        for (int n = 0; n < NHALF; ++n) {
            float lr  = -expf(prm[0][n]) * 0.1f;
            float amp = expf(lr * (float)tau);
            double ph = (double)prm[1][n] * 0.1 * (double)tau;
            ph -= floor(ph * (1.0/(2.0*M_PI))) * (2.0*M_PI);
            float sv, cv; sincosf((float)ph, &sv, &cv);
            float cr = prm[2][n], ci = prm[3][n];
            aR = fmaf(amp, cr*cv - ci*sv, aR);
            aI = fmaf(amp, cr*sv + ci*cv, aI);
        }
        hRe[tau] = aR; hIm[tau] = aI;
    }
    __syncthreads();
    float base[8], hsum[8];
    #pragma unroll
    for (int r = 0; r < 8; ++r) {
        base[r] = (r < 4) ? hRe[tid + 256*r] : 0.f;
        hsum[r] = 0.f;
    }
    const int tau0 = (tid & 1) ^ 1;
    for (int tau = tau0; tau < TMAX; tau += 2) {
        float him = hIm[tau];
        #pragma unroll
        for (int r = 0; r < 8; ++r) {
            int idx = ((tid + 256*r - tau) & (2*LSEQ - 1)) >> 1;
            hsum[r] = fmaf(ct[idx], him, hsum[r]);
        }
    }
    #pragma unroll
    for (int r = 0; r < 8; ++r) {
        int t = tid + 256*r;
        kT[(t + KPAD)*DMODEL + d] = base[r] - hsum[r] * (1.0f/(float)LSEQ);
    }
    if (tid < 2*KPAD) {
        int row = (tid < KPAD) ? tid : (LSEQ + KPAD + (tid - KPAD));
        kT[row*DMODEL + d] = 0.f;
    }
}

__global__ __launch_bounds__(256) void s4d_conv(
    const float* __restrict__ u, const float* __restrict__ Dvec,
    const float* __restrict__ kT, float* __restrict__ out)
{
    const int d  = threadIdx.x;
    const int t0 = blockIdx.x * TT;
    const int b  = blockIdx.y;
    float dvv = Dvec[d];
    float acc[TT];
    #pragma unroll
    for (int i = 0; i < TT; ++i) acc[i] = dvv;
    const float* ub   = u + (size_t)b * LSEQ * DMODEL + d;
    const float* kcol = kT + d;
    int mstart = t0 - 1024; if (mstart < 0) mstart = 0;
    int mend   = t0 + 1040; if (mend > LSEQ) mend = LSEQ;
    float kreg[31];
    {
        int jpb = mstart - t0 + 1024;
        #pragma unroll
        for (int r = 0; r < 31; ++r) kreg[r] = kcol[(jpb + r)*DMODEL];
    }
    for (int m0 = mstart; m0 < mend; m0 += TT) {
        float ureg[TT];
        #pragma unroll
        for (int mm = 0; mm < TT; ++mm) ureg[mm] = ub[(m0 + mm)*DMODEL];
        float knew[TT];
        if (m0 + TT < mend) {
            int jnb = m0 - t0 + 1024 + 31;
            #pragma unroll
            for (int r = 0; r < TT; ++r) knew[r] = kcol[(jnb + r)*DMODEL];
        } else {
            #pragma unroll
            for (int r = 0; r < TT; ++r) knew[r] = 0.f;
        }
        #pragma unroll
        for (int mm = 0; mm < TT; ++mm)
            #pragma unroll
            for (int tt = 0; tt < TT; ++tt)
                acc[tt] = fmaf(ureg[mm], kreg[mm - tt + 15], acc[tt]);
        #pragma unroll
        for (int r = 0; r < 15; ++r) kreg[r] = kreg[r + 16];
        #pragma unroll
        for (int r = 0; r < 16; ++r) kreg[15 + r] = knew[r];
    }
    float* ob = out + ((size_t)b * LSEQ + t0) * DMODEL + d;
    #pragma unroll
    for (int tt = 0; tt < TT; ++tt) ob[tt*DMODEL] = acc[tt];
}

// ============================================================ launch
extern "C" void kernel_launch(void* const* d_in, const int* in_sizes, int n_in,
                              void* d_out, int out_size, void* d_ws, size_t ws_size,
                              hipStream_t stream)
{
    const float* u  = (const float*)d_in[0];
    const float* Ar = (const float*)d_in[1];
    const float* Ai = (const float*)d_in[2];
    const float* Cr = (const float*)d_in[3];
    const float* Ci = (const float*)d_in[4];
    const float* Dv = (const float*)d_in[5];
    float* out = (float*)d_out;
    int B = in_sizes[0] / (LSEQ * DMODEL);

    if (B == 8 && ws_size >= WS_NEED) {
        unsigned short* uimg = (unsigned short*)d_ws;
        unsigned short* kb2g = uimg + UIMG_SHORTS;
        s4d_utr<<<dim3(LSEQ/64, 8), 256, 0, stream>>>(u, uimg);
        s4d_build_kb<<<DMODEL, 512, 0, stream>>>(Ar, Ai, Cr, Ci, kb2g);
        s4d_mfma<<<DMODEL, 512, 0, stream>>>(uimg, kb2g, Dv, out);
    } else {
        float* kT = (float*)d_ws;
        s4d_build_k<<<DMODEL, 256, 0, stream>>>(Ar, Ai, Cr, Ci, kT);
        s4d_conv<<<dim3(LSEQ/TT, B), 256, 0, stream>>>(u, Dv, kT, out);
    }
}

// Round 3
// 62.808 us; speedup vs baseline: 5.6237x; 1.7110x over previous
//
#include <hip/hip_runtime.h>
#include <hip/hip_bf16.h>
#include <math.h>

#define LSEQ   2048
#define DMODEL 256
#define NHALF  32
#define TMAX   1024                 // fallback-path truncation
#define TM2    384                  // fast-path truncation (amp ~ 4.6e-9)
#define KPAD   16
#define KROWS  (LSEQ + 2*KPAD)
#define TT     16
#define CTL_N  1232                 // 1220 used, padded

typedef __attribute__((ext_vector_type(8))) short short8;
typedef __attribute__((ext_vector_type(4))) float f32x4;
typedef __attribute__((ext_vector_type(4))) unsigned int u32x4;

// ---- MFMA-path geometry
#define UB_ROWS   8
#define UB_STR    2056
#define UB_SHORTS (UB_ROWS*UB_STR)
#define UB_BYTES  (UB_SHORTS*2)
#define KB_LEN    4352
#define KB_SHORTS (2*KB_LEN)
#define KB_BYTES  (KB_SHORTS*2)
#define SM_TOTAL  (UB_BYTES + KB_BYTES)
#define UIMG_SHORTS ((size_t)DMODEL*UB_SHORTS)
#define KB2G_SHORTS ((size_t)DMODEL*KB_SHORTS)
#define WS_NEED   ((UIMG_SHORTS + KB2G_SHORTS)*2)

// ============================================================ stage 0:
// u [B][L][D] f32  ->  uimg [d][b][m] bf16 (row stride UB_STR)
__global__ __launch_bounds__(256) void s4d_utr(const float* __restrict__ u,
                                               unsigned short* __restrict__ uimg)
{
    __shared__ unsigned short tr[DMODEL][66];
    const int tid = threadIdx.x;
    const int m0  = blockIdx.x * 64;
    const int b   = blockIdx.y;

    const int mmBase = tid >> 6;
    const int d4     = (tid & 63) * 4;
    for (int it = 0; it < 16; ++it) {
        int mm = it*4 + mmBase;
        const float* src = u + ((size_t)b*LSEQ + m0 + mm)*DMODEL + d4;
        f32x4 v = *(const f32x4*)src;
        #pragma unroll
        for (int j = 0; j < 4; ++j) {
            __hip_bfloat16 hb = __float2bfloat16(v[j]);
            tr[d4+j][mm] = *(unsigned short*)&hb;
        }
    }
    __syncthreads();
    // phase 2: chunk-major for coalesced 128B segments per 8 lanes
    #pragma unroll
    for (int P = 0; P < 8; ++P) {
        int d = P*32 + (tid >> 3);
        int c = tid & 7;
        const unsigned short* s = &tr[d][c*8];
        u32x4 w = { *(const unsigned*)(s),   *(const unsigned*)(s+2),
                    *(const unsigned*)(s+4), *(const unsigned*)(s+6) };
        *(u32x4*)(uimg + (size_t)d*UB_SHORTS + (size_t)b*UB_STR + m0 + c*8) = w;
    }
}

// ============================================================ stage 1 (rewritten):
// k[t] = Re h[t] - (1/L)*sum_{tau: t-tau odd, tau<TM2} cot(pi*(t-tau)/2L)*Im h[tau]
// Register-blocked: thread handles t = 8g+pt+{0,2,4,6}; sliding 8-reg ct window.
__global__ __launch_bounds__(512) void s4d_build_kb2(
    const float* __restrict__ A_real, const float* __restrict__ A_imag,
    const float* __restrict__ C_real, const float* __restrict__ C_imag,
    unsigned short* __restrict__ kb2g)
{
    __shared__ __align__(16) float ctL0[CTL_N];
    __shared__ __align__(16) float ctL1[CTL_N];
    __shared__ __align__(16) float hRe[TM2];
    __shared__ __align__(16) float hImE[TM2/2];
    __shared__ __align__(16) float hImO[TM2/2];
    __shared__ float prm[4][NHALF];

    const int tid = threadIdx.x;
    const int d   = blockIdx.x;

    if (tid < NHALF) {
        prm[0][tid] = A_real[d*NHALF + tid];
        prm[1][tid] = A_imag[d*NHALF + tid];
        prm[2][tid] = C_real[d*NHALF + tid];
        prm[3][tid] = C_imag[d*NHALF + tid];
    }
    // per-parity shifted cot tables: ctL0[i]=cot(pi*(2x+1)/4096), x=(i-196)&2047
    //                                ctL1[i]=same with x=(i-195)&2047
    for (int i = tid; i < 1220; i += 512) {
        int x0 = (i - 196) & 2047;
        int x1 = (i - 195) & 2047;
        float a0 = (float)(M_PI/(2.0*(double)LSEQ)) * (float)(2*x0 + 1);
        float a1 = (float)(M_PI/(2.0*(double)LSEQ)) * (float)(2*x1 + 1);
        float s0, c0, s1, c1;
        sincosf(a0, &s0, &c0);
        sincosf(a1, &s1, &c1);
        ctL0[i] = c0 / s0;
        ctL1[i] = c1 / s1;
    }
    __syncthreads();

    if (tid < TM2) {
        const int tau = tid;
        float aR = 0.f, aI = 0.f;
        for (int n = 0; n < NHALF; ++n) {
            float lr  = -expf(prm[0][n]) * 0.1f;
            float amp = expf(lr * (float)tau);
            double ph = (double)prm[1][n] * 0.1 * (double)tau;
            ph -= floor(ph * (1.0/(2.0*M_PI))) * (2.0*M_PI);
            float s, c; sincosf((float)ph, &s, &c);
            float cr = prm[2][n], ci = prm[3][n];
            aR = fmaf(amp, cr*c - ci*s, aR);
            aI = fmaf(amp, cr*s + ci*c, aI);
        }
        hRe[tau] = aR;
        if (tau & 1) hImO[tau >> 1] = aI;
        else         hImE[tau >> 1] = aI;
    }
    __syncthreads();

    const int pt = tid & 1;
    const int g  = tid >> 1;
    const float* tb = pt ? ctL1 : ctL0;
    const float* hb = pt ? hImE : hImO;   // pt=1 -> tau even; pt=0 -> tau odd

    float acc0 = 0.f, acc1 = 0.f, acc2 = 0.f, acc3 = 0.f;
    int qb = 4*g + 192;
    f32x4 Wlo = *(const f32x4*)(tb + qb);
    f32x4 Whi = *(const f32x4*)(tb + qb + 4);

    #pragma unroll 4
    for (int R = 0; R < 48; ++R) {
        f32x4 hv = *(const f32x4*)(hb + 4*R);
        f32x4 Wn = *(const f32x4*)(tb + qb - 4);   // qb-4 >= 4g >= 0
        // offsets o = 3 + e - rr into W[0..7] (Wlo=0..3, Whi=4..7)
        acc0 = fmaf(Wlo[3], hv[0], acc0); acc1 = fmaf(Whi[0], hv[0], acc1);
        acc2 = fmaf(Whi[1], hv[0], acc2); acc3 = fmaf(Whi[2], hv[0], acc3);
        acc0 = fmaf(Wlo[2], hv[1], acc0); acc1 = fmaf(Wlo[3], hv[1], acc1);
        acc2 = fmaf(Whi[0], hv[1], acc2); acc3 = fmaf(Whi[1], hv[1], acc3);
        acc0 = fmaf(Wlo[1], hv[2], acc0); acc1 = fmaf(Wlo[2], hv[2], acc1);
        acc2 = fmaf(Wlo[3], hv[2], acc2); acc3 = fmaf(Whi[0], hv[2], acc3);
        acc0 = fmaf(Wlo[0], hv[3], acc0); acc1 = fmaf(Wlo[1], hv[3], acc1);
        acc2 = fmaf(Wlo[2], hv[3], acc2); acc3 = fmaf(Wlo[3], hv[3], acc3);
        Whi = Wlo; Wlo = Wn; qb -= 4;
    }

    unsigned short* row = kb2g + (size_t)d*KB_SHORTS;
    float accs[4] = {acc0, acc1, acc2, acc3};
    #pragma unroll
    for (int e = 0; e < 4; ++e) {
        int t = 8*g + 2*e + pt;
        float base = (t < TM2) ? hRe[t] : 0.f;
        float kv = base - accs[e] * (1.0f/(float)LSEQ);
        __hip_bfloat16 hbv = __float2bfloat16(kv);
        unsigned short us = *(unsigned short*)&hbv;
        row[t + 1024] = us;                    // s=0 copy
        row[KB_LEN + t + 1023] = us;           // s=1 copy
    }
    // zero pads
    for (int x = tid; x < 1024; x += 512)        row[x] = 0;
    for (int x = 3072 + tid; x < KB_LEN; x += 512) row[x] = 0;
    for (int x = tid; x < 1023; x += 512)        row[KB_LEN + x] = 0;
    for (int x = 3071 + tid; x < KB_LEN; x += 512) row[KB_LEN + x] = 0;
}

// ============================================================ stage 2 (unchanged, verified):
__device__ __forceinline__ short8 loadA4(const unsigned char* sm, int addr) {
    unsigned a0 = *(const unsigned*)(sm + addr);
    unsigned a1 = *(const unsigned*)(sm + addr + 4);
    unsigned a2 = *(const unsigned*)(sm + addr + 8);
    unsigned a3 = *(const unsigned*)(sm + addr + 12);
    u32x4 v = {a0, a1, a2, a3};
    return __builtin_bit_cast(short8, v);
}
__device__ __forceinline__ short8 loadB16(const unsigned char* sm, int addr) {
    return *(const short8*)(sm + addr);
}
#define MF(a, b, c) __builtin_amdgcn_mfma_f32_16x16x32_bf16((a), (b), (c), 0, 0, 0)

__global__ __launch_bounds__(512, 2) void s4d_mfma(
    const unsigned short* __restrict__ uimg, const unsigned short* __restrict__ kb2g,
    const float* __restrict__ Dvec, float* __restrict__ out)
{
    __shared__ __align__(16) unsigned char sm[SM_TOTAL];
    const int tid = threadIdx.x;
    const int Bk  = blockIdx.x;
    const int d   = ((Bk & 7) << 5) | (Bk >> 3);

    {
        const u32x4* gu = (const u32x4*)(uimg + (size_t)d*UB_SHORTS);
        u32x4* lu = (u32x4*)sm;
        for (int i = tid; i < UB_SHORTS/8; i += 512) lu[i] = gu[i];
        const u32x4* gk = (const u32x4*)(kb2g + (size_t)d*KB_SHORTS);
        u32x4* lk = (u32x4*)(sm + UB_BYTES);
        for (int i = tid; i < KB_SHORTS/8; i += 512) lk[i] = gk[i];
    }
    __syncthreads();

    const int lane = tid & 63, wv = tid >> 6;
    const int h    = lane >> 4;
    const int col  = lane & 15;
    const int t0w  = wv << 8;

    const int s     = (col + 1) & 1;
    const int laneC = UB_BYTES + s*(KB_LEN*2) - 2*s + 2*((h << 3) - col);
    const int baseA = laneC + 2*(2047 - t0w);
    const int laneB = (col & 7)*(UB_STR*2) + (h << 4);

    const float dv = Dvec[d];
    f32x4 acc[16];
    #pragma unroll
    for (int tt = 0; tt < 16; ++tt) acc[tt] = (f32x4){dv, dv, dv, dv};

    short8 A[16], Bb[2];
    #pragma unroll
    for (int tt = 0; tt < 16; ++tt) A[tt] = loadA4(sm, baseA - 32*tt);
    Bb[0] = loadB16(sm, laneB);

    int aA = baseA + 64;
    int aB = laneB + 64;

    for (int Q = 0; Q < 8; ++Q) {
        #pragma unroll
        for (int p = 0; p < 8; ++p) {
            const short8 bcur = Bb[p & 1];
            acc[14] = MF(A[(14 - 2*p) & 15], bcur, acc[14]);
            acc[15] = MF(A[(15 - 2*p) & 15], bcur, acc[15]);
            A[(14 - 2*p) & 15] = loadA4(sm, aA);
            A[(15 - 2*p) & 15] = loadA4(sm, aA - 32);
            Bb[(p + 1) & 1]    = loadB16(sm, aB);
            aA += 64; aB += 64;
            #pragma unroll
            for (int tt = 2; tt < 14; ++tt)
                acc[tt] = MF(A[(tt - 2*p) & 15], bcur, acc[tt]);
            acc[0] = MF(A[(0 - 2*p) & 15], bcur, acc[0]);
            acc[1] = MF(A[(1 - 2*p) & 15], bcur, acc[1]);
        }
    }

    if (col < 8) {
        float* ob = out + (size_t)col*LSEQ*DMODEL + d;
        #pragma unroll
        for (int tt = 0; tt < 16; ++tt) {
            int trow = t0w + tt*16 + h*4;
            float* o = ob + (size_t)trow*DMODEL;
            o[0*DMODEL] = acc[tt][0];
            o[1*DMODEL] = acc[tt][1];
            o[2*DMODEL] = acc[tt][2];
            o[3*DMODEL] = acc[tt][3];
        }
    }
}

// ============================================================ fallback (R1, verified)
__global__ __launch_bounds__(256) void s4d_build_k(
    const float* __restrict__ A_real, const float* __restrict__ A_imag,
    const float* __restrict__ C_real, const float* __restrict__ C_imag,
    float* __restrict__ kT)
{
    __shared__ float hRe[TMAX], hIm[TMAX], ct[LSEQ], prm[4][NHALF];
    const int tid = threadIdx.x;
    const int d   = blockIdx.x;
    if (tid < NHALF) {
        prm[0][tid] = A_real[d*NHALF + tid];
        prm[1][tid] = A_imag[d*NHALF + tid];
        prm[2][tid] = C_real[d*NHALF + tid];
        prm[3][tid] = C_imag[d*NHALF + tid];
    }
    #pragma unroll
    for (int r = 0; r < LSEQ/256; ++r) {
        int i = tid + 256*r;
        float ang = (float)(M_PI/(2.0*(double)LSEQ)) * (float)(2*i + 1);
        float sv, cv; sincosf(ang, &sv, &cv);
        ct[i] = cv / sv;
    }
    __syncthreads();
    for (int r = 0; r < TMAX/256; ++r) {
        int tau = tid + 256*r;
        float aR = 0.f, aI = 0.f;
        for (int n = 0; n < NHALF; ++n) {
            float lr  = -expf(prm[0][n]) * 0.1f;
            float amp = expf(lr * (float)tau);
            double ph = (double)prm[1][n] * 0.1 * (double)tau;
            ph -= floor(ph * (1.0/(2.0*M_PI))) * (2.0*M_PI);
            float sv, cv; sincosf((float)ph, &sv, &cv);
            float cr = prm[2][n], ci = prm[3][n];
            aR = fmaf(amp, cr*cv - ci*sv, aR);
            aI = fmaf(amp, cr*sv + ci*cv, aI);
        }
        hRe[tau] = aR; hIm[tau] = aI;
    }
    __syncthreads();
    float base[8], hsum[8];
    #pragma unroll
    for (int r = 0; r < 8; ++r) {
        base[r] = (r < 4) ? hRe[tid + 256*r] : 0.f;
        hsum[r] = 0.f;
    }
    const int tau0 = (tid & 1) ^ 1;
    for (int tau = tau0; tau < TMAX; tau += 2) {
        float him = hIm[tau];
        #pragma unroll
        for (int r = 0; r < 8; ++r) {
            int idx = ((tid + 256*r - tau) & (2*LSEQ - 1)) >> 1;
            hsum[r] = fmaf(ct[idx], him, hsum[r]);
        }
    }
    #pragma unroll
    for (int r = 0; r < 8; ++r) {
        int t = tid + 256*r;
        kT[(t + KPAD)*DMODEL + d] = base[r] - hsum[r] * (1.0f/(float)LSEQ);
    }
    if (tid < 2*KPAD) {
        int row = (tid < KPAD) ? tid : (LSEQ + KPAD + (tid - KPAD));
        kT[row*DMODEL + d] = 0.f;
    }
}

__global__ __launch_bounds__(256) void s4d_conv(
    const float* __restrict__ u, const float* __restrict__ Dvec,
    const float* __restrict__ kT, float* __restrict__ out)
{
    const int d  = threadIdx.x;
    const int t0 = blockIdx.x * TT;
    const int b  = blockIdx.y;
    float dvv = Dvec[d];
    float acc[TT];
    #pragma unroll
    for (int i = 0; i < TT; ++i) acc[i] = dvv;
    const float* ub   = u + (size_t)b * LSEQ * DMODEL + d;
    const float* kcol = kT + d;
    int mstart = t0 - 1024; if (mstart < 0) mstart = 0;
    int mend   = t0 + 1040; if (mend > LSEQ) mend = LSEQ;
    float kreg[31];
    {
        int jpb = mstart - t0 + 1024;
        #pragma unroll
        for (int r = 0; r < 31; ++r) kreg[r] = kcol[(jpb + r)*DMODEL];
    }
    for (int m0 = mstart; m0 < mend; m0 += TT) {
        float ureg[TT];
        #pragma unroll
        for (int mm = 0; mm < TT; ++mm) ureg[mm] = ub[(m0 + mm)*DMODEL];
        float knew[TT];
        if (m0 + TT < mend) {
            int jnb = m0 - t0 + 1024 + 31;
            #pragma unroll
            for (int r = 0; r < TT; ++r) knew[r] = kcol[(jnb + r)*DMODEL];
        } else {
            #pragma unroll
            for (int r = 0; r < TT; ++r) knew[r] = 0.f;
        }
        #pragma unroll
        for (int mm = 0; mm < TT; ++mm)
            #pragma unroll
            for (int tt = 0; tt < TT; ++tt)
                acc[tt] = fmaf(ureg[mm], kreg[mm - tt + 15], acc[tt]);
        #pragma unroll
        for (int r = 0; r < 15; ++r) kreg[r] = kreg[r + 16];
        #pragma unroll
        for (int r = 0; r < 16; ++r) kreg[15 + r] = knew[r];
    }
    float* ob = out + ((size_t)b * LSEQ + t0) * DMODEL + d;
    #pragma unroll
    for (int tt = 0; tt < TT; ++tt) ob[tt*DMODEL] = acc[tt];
}

// ============================================================ launch
extern "C" void kernel_launch(void* const* d_in, const int* in_sizes, int n_in,
                              void* d_out, int out_size, void* d_ws, size_t ws_size,
                              hipStream_t stream)
{
    const float* u  = (const float*)d_in[0];
    const float* Ar = (const float*)d_in[1];
    const float* Ai = (const float*)d_in[2];
    const float* Cr = (const float*)d_in[3];
    const float* Ci = (const float*)d_in[4];
    const float* Dv = (const float*)d_in[5];
    float* out = (float*)d_out;
    int B = in_sizes[0] / (LSEQ * DMODEL);

    if (B == 8 && ws_size >= WS_NEED) {
        unsigned short* uimg = (unsigned short*)d_ws;
        unsigned short* kb2g = uimg + UIMG_SHORTS;
        s4d_utr<<<dim3(LSEQ/64, 8), 256, 0, stream>>>(u, uimg);
        s4d_build_kb2<<<DMODEL, 512, 0, stream>>>(Ar, Ai, Cr, Ci, kb2g);
        s4d_mfma<<<DMODEL, 512, 0, stream>>>(uimg, kb2g, Dv, out);
    } else {
        float* kT = (float*)d_ws;
        s4d_build_k<<<DMODEL, 256, 0, stream>>>(Ar, Ai, Cr, Ci, kT);
        s4d_conv<<<dim3(LSEQ/TT, B), 256, 0, stream>>>(u, Dv, kT, out);
    }
}

// Round 4
// 61.649 us; speedup vs baseline: 5.7295x; 1.0188x over previous
//
#include <hip/hip_runtime.h>
#include <hip/hip_bf16.h>
#include <math.h>

#define LSEQ   2048
#define DMODEL 256
#define NHALF  32
#define TMAX   1024                 // fallback-path truncation
#define TM2    384                  // fast-path truncation (amp ~ 4.6e-9)
#define KPAD   16
#define KROWS  (LSEQ + 2*KPAD)
#define TT     16
#define CTL_N  1232                 // 1220 used, padded

typedef __attribute__((ext_vector_type(8))) short short8;
typedef __attribute__((ext_vector_type(4))) float f32x4;
typedef __attribute__((ext_vector_type(4))) unsigned int u32x4;

// ---- MFMA-path geometry (verified R2/R3)
#define UB_ROWS   8
#define UB_STR    2056
#define UB_SHORTS (UB_ROWS*UB_STR)
#define UB_BYTES  (UB_SHORTS*2)          // 32896
#define KB_LEN    4352
#define KB_SHORTS (2*KB_LEN)
#define KB_BYTES  (KB_SHORTS*2)          // 17408
#define SM_TOTAL  (UB_BYTES + KB_BYTES)  // 50304

__device__ __forceinline__ short8 loadA4(const unsigned char* sm, int addr) {
    unsigned a0 = *(const unsigned*)(sm + addr);
    unsigned a1 = *(const unsigned*)(sm + addr + 4);
    unsigned a2 = *(const unsigned*)(sm + addr + 8);
    unsigned a3 = *(const unsigned*)(sm + addr + 12);
    u32x4 v = {a0, a1, a2, a3};
    return __builtin_bit_cast(short8, v);
}
__device__ __forceinline__ short8 loadB16(const unsigned char* sm, int addr) {
    return *(const short8*)(sm + addr);
}
#define MF(a, b, c) __builtin_amdgcn_mfma_f32_16x16x32_bf16((a), (b), (c), 0, 0, 0)

// ============================================================ fused kernel:
// one block per d. Waves 0-3: gather u[b,:,d] -> LDS bf16. Waves 4-7: build
// k (cot tables + 32-mode eval + register-blocked Hilbert) -> LDS bf16,
// two parity-shifted zero-padded copies. Then verified Toeplitz-MFMA loop.
__global__ __launch_bounds__(512, 2) void s4d_fused(
    const float* __restrict__ u,
    const float* __restrict__ A_real, const float* __restrict__ A_imag,
    const float* __restrict__ C_real, const float* __restrict__ C_imag,
    const float* __restrict__ Dvec, float* __restrict__ out)
{
    __shared__ __align__(16) unsigned char sm[SM_TOTAL];
    __shared__ __align__(16) float ctL0[CTL_N];
    __shared__ __align__(16) float ctL1[CTL_N];
    __shared__ __align__(16) float hRe[TM2];
    __shared__ __align__(16) float hImE[TM2/2];
    __shared__ __align__(16) float hImO[TM2/2];

    const int tid = threadIdx.x;
    const int Bk  = blockIdx.x;
    const int d   = ((Bk & 7) << 5) | (Bk >> 3);   // XCD-swizzle: 32 consecutive d per XCD

    unsigned short* ub16 = (unsigned short*)sm;
    unsigned short* kb16 = (unsigned short*)(sm + UB_BYTES);

    // ---------------- phase 1
    if (tid < 256) {
        // u gather, part 1 (b = 0..3): strided 4B loads, d-neighbor blocks share lines in XCD-L2
        for (int r = 0; r < 32; ++r) {
            int idx = tid + 256*r;
            int b = idx >> 11, m = idx & 2047;
            float v = u[((size_t)b*LSEQ + m)*DMODEL + d];
            __hip_bfloat16 hb = __float2bfloat16(v);
            ub16[b*UB_STR + m] = *(unsigned short*)&hb;
        }
    } else {
        const int t2 = tid - 256;
        // per-parity shifted cot tables
        for (int i = t2; i < 1220; i += 256) {
            int x0 = (i - 196) & 2047;
            int x1 = (i - 195) & 2047;
            float a0 = (float)(M_PI/(2.0*(double)LSEQ)) * (float)(2*x0 + 1);
            float a1 = (float)(M_PI/(2.0*(double)LSEQ)) * (float)(2*x1 + 1);
            float s0, c0, s1, c1;
            sincosf(a0, &s0, &c0);
            sincosf(a1, &s1, &c1);
            ctL0[i] = c0 / s0;
            ctL1[i] = c1 / s1;
        }
        // 32-mode eval, h[tau] for tau < TM2 (two passes on 256 threads)
        #pragma unroll
        for (int ps = 0; ps < 2; ++ps) {
            int tau = t2 + 256*ps;
            if (tau < TM2) {
                float aR = 0.f, aI = 0.f;
                for (int n = 0; n < NHALF; ++n) {
                    float lr  = -expf(A_real[d*NHALF + n]) * 0.1f;
                    float amp = expf(lr * (float)tau);
                    double ph = (double)A_imag[d*NHALF + n] * 0.1 * (double)tau;
                    ph -= floor(ph * (1.0/(2.0*M_PI))) * (2.0*M_PI);
                    float s, c; sincosf((float)ph, &s, &c);
                    float cr = C_real[d*NHALF + n], ci = C_imag[d*NHALF + n];
                    aR = fmaf(amp, cr*c - ci*s, aR);
                    aI = fmaf(amp, cr*s + ci*c, aI);
                }
                hRe[tau] = aR;
                if (tau & 1) hImO[tau >> 1] = aI;
                else         hImE[tau >> 1] = aI;
            }
        }
    }
    __syncthreads();

    // ---------------- phase 2
    if (tid < 256) {
        // u gather, part 2 (b = 4..7)
        for (int r = 32; r < 64; ++r) {
            int idx = tid + 256*r;
            int b = idx >> 11, m = idx & 2047;
            float v = u[((size_t)b*LSEQ + m)*DMODEL + d];
            __hip_bfloat16 hb = __float2bfloat16(v);
            ub16[b*UB_STR + m] = *(unsigned short*)&hb;
        }
    } else {
        const int t2 = tid - 256;
        // register-blocked Hilbert tail (verified R3 body, two passes)
        #pragma unroll
        for (int ps = 0; ps < 2; ++ps) {
            const int v  = t2 + 256*ps;
            const int pt = v & 1;
            const int g  = v >> 1;
            const float* tb = pt ? ctL1 : ctL0;
            const float* hb = pt ? hImE : hImO;

            float acc0 = 0.f, acc1 = 0.f, acc2 = 0.f, acc3 = 0.f;
            int qb = 4*g + 192;
            f32x4 Wlo = *(const f32x4*)(tb + qb);
            f32x4 Whi = *(const f32x4*)(tb + qb + 4);

            #pragma unroll 4
            for (int R = 0; R < 48; ++R) {
                f32x4 hv = *(const f32x4*)(hb + 4*R);
                f32x4 Wn = *(const f32x4*)(tb + qb - 4);
                acc0 = fmaf(Wlo[3], hv[0], acc0); acc1 = fmaf(Whi[0], hv[0], acc1);
                acc2 = fmaf(Whi[1], hv[0], acc2); acc3 = fmaf(Whi[2], hv[0], acc3);
                acc0 = fmaf(Wlo[2], hv[1], acc0); acc1 = fmaf(Wlo[3], hv[1], acc1);
                acc2 = fmaf(Whi[0], hv[1], acc2); acc3 = fmaf(Whi[1], hv[1], acc3);
                acc0 = fmaf(Wlo[1], hv[2], acc0); acc1 = fmaf(Wlo[2], hv[2], acc1);
                acc2 = fmaf(Wlo[3], hv[2], acc2); acc3 = fmaf(Whi[0], hv[2], acc3);
                acc0 = fmaf(Wlo[0], hv[3], acc0); acc1 = fmaf(Wlo[1], hv[3], acc1);
                acc2 = fmaf(Wlo[2], hv[3], acc2); acc3 = fmaf(Wlo[3], hv[3], acc3);
                Whi = Wlo; Wlo = Wn; qb -= 4;
            }

            float accs[4] = {acc0, acc1, acc2, acc3};
            #pragma unroll
            for (int e = 0; e < 4; ++e) {
                int t = 8*g + 2*e + pt;
                float base = (t < TM2) ? hRe[t] : 0.f;
                float kv = base - accs[e] * (1.0f/(float)LSEQ);
                __hip_bfloat16 hbv = __float2bfloat16(kv);
                unsigned short us = *(unsigned short*)&hbv;
                kb16[t + 1024] = us;                 // s=0 copy
                kb16[KB_LEN + t + 1023] = us;        // s=1 copy
            }
        }
        // zero pads (the read window touches [8,1024) and [3072,4088))
        for (int x = t2; x < 1024; x += 256)           kb16[x] = 0;
        for (int x = 3072 + t2; x < KB_LEN; x += 256)  kb16[x] = 0;
        for (int x = t2; x < 1023; x += 256)           kb16[KB_LEN + x] = 0;
        for (int x = 3071 + t2; x < KB_LEN; x += 256)  kb16[KB_LEN + x] = 0;
    }
    __syncthreads();

    // ---------------- main loop (byte-identical to verified s4d_mfma)
    const int lane = tid & 63, wv = tid >> 6;
    const int h    = lane >> 4;
    const int col  = lane & 15;
    const int t0w  = wv << 8;

    const int s     = (col + 1) & 1;
    const int laneC = UB_BYTES + s*(KB_LEN*2) - 2*s + 2*((h << 3) - col);
    const int baseA = laneC + 2*(2047 - t0w);
    const int laneB = (col & 7)*(UB_STR*2) + (h << 4);

    const float dv = Dvec[d];
    f32x4 acc[16];
    #pragma unroll
    for (int tt = 0; tt < 16; ++tt) acc[tt] = (f32x4){dv, dv, dv, dv};

    short8 A[16], Bb[2];
    #pragma unroll
    for (int tt = 0; tt < 16; ++tt) A[tt] = loadA4(sm, baseA - 32*tt);
    Bb[0] = loadB16(sm, laneB);

    int aA = baseA + 64;
    int aB = laneB + 64;

    for (int Q = 0; Q < 8; ++Q) {
        #pragma unroll
        for (int p = 0; p < 8; ++p) {
            const short8 bcur = Bb[p & 1];
            acc[14] = MF(A[(14 - 2*p) & 15], bcur, acc[14]);
            acc[15] = MF(A[(15 - 2*p) & 15], bcur, acc[15]);
            A[(14 - 2*p) & 15] = loadA4(sm, aA);
            A[(15 - 2*p) & 15] = loadA4(sm, aA - 32);
            Bb[(p + 1) & 1]    = loadB16(sm, aB);
            aA += 64; aB += 64;
            #pragma unroll
            for (int tt = 2; tt < 14; ++tt)
                acc[tt] = MF(A[(tt - 2*p) & 15], bcur, acc[tt]);
            acc[0] = MF(A[(0 - 2*p) & 15], bcur, acc[0]);
            acc[1] = MF(A[(1 - 2*p) & 15], bcur, acc[1]);
        }
    }

    if (col < 8) {
        float* ob = out + (size_t)col*LSEQ*DMODEL + d;
        #pragma unroll
        for (int tt = 0; tt < 16; ++tt) {
            int trow = t0w + tt*16 + h*4;
            float* o = ob + (size_t)trow*DMODEL;
            o[0*DMODEL] = acc[tt][0];
            o[1*DMODEL] = acc[tt][1];
            o[2*DMODEL] = acc[tt][2];
            o[3*DMODEL] = acc[tt][3];
        }
    }
}

// ============================================================ fallback (R1, verified)
__global__ __launch_bounds__(256) void s4d_build_k(
    const float* __restrict__ A_real, const float* __restrict__ A_imag,
    const float* __restrict__ C_real, const float* __restrict__ C_imag,
    float* __restrict__ kT)
{
    __shared__ float hRe[TMAX], hIm[TMAX], ct[LSEQ], prm[4][NHALF];
    const int tid = threadIdx.x;
    const int d   = blockIdx.x;
    if (tid < NHALF) {
        prm[0][tid] = A_real[d*NHALF + tid];
        prm[1][tid] = A_imag[d*NHALF + tid];
        prm[2][tid] = C_real[d*NHALF + tid];
        prm[3][tid] = C_imag[d*NHALF + tid];
    }
    #pragma unroll
    for (int r = 0; r < LSEQ/256; ++r) {
        int i = tid + 256*r;
        float ang = (float)(M_PI/(2.0*(double)LSEQ)) * (float)(2*i + 1);
        float sv, cv; sincosf(ang, &sv, &cv);
        ct[i] = cv / sv;
    }
    __syncthreads();
    for (int r = 0; r < TMAX/256; ++r) {
        int tau = tid + 256*r;
        float aR = 0.f, aI = 0.f;
        for (int n = 0; n < NHALF; ++n) {
            float lr  = -expf(prm[0][n]) * 0.1f;
            float amp = expf(lr * (float)tau);
            double ph = (double)prm[1][n] * 0.1 * (double)tau;
            ph -= floor(ph * (1.0/(2.0*M_PI))) * (2.0*M_PI);
            float sv, cv; sincosf((float)ph, &sv, &cv);
            float cr = prm[2][n], ci = prm[3][n];
            aR = fmaf(amp, cr*cv - ci*sv, aR);
            aI = fmaf(amp, cr*sv + ci*cv, aI);
        }
        hRe[tau] = aR; hIm[tau] = aI;
    }
    __syncthreads();
    float base[8], hsum[8];
    #pragma unroll
    for (int r = 0; r < 8; ++r) {
        base[r] = (r < 4) ? hRe[tid + 256*r] : 0.f;
        hsum[r] = 0.f;
    }
    const int tau0 = (tid & 1) ^ 1;
    for (int tau = tau0; tau < TMAX; tau += 2) {
        float him = hIm[tau];
        #pragma unroll
        for (int r = 0; r < 8; ++r) {
            int idx = ((tid + 256*r - tau) & (2*LSEQ - 1)) >> 1;
            hsum[r] = fmaf(ct[idx], him, hsum[r]);
        }
    }
    #pragma unroll
    for (int r = 0; r < 8; ++r) {
        int t = tid + 256*r;
        kT[(t + KPAD)*DMODEL + d] = base[r] - hsum[r] * (1.0f/(float)LSEQ);
    }
    if (tid < 2*KPAD) {
        int row = (tid < KPAD) ? tid : (LSEQ + KPAD + (tid - KPAD));
        kT[row*DMODEL + d] = 0.f;
    }
}

__global__ __launch_bounds__(256) void s4d_conv(
    const float* __restrict__ u, const float* __restrict__ Dvec,
    const float* __restrict__ kT, float* __restrict__ out)
{
    const int d  = threadIdx.x;
    const int t0 = blockIdx.x * TT;
    const int b  = blockIdx.y;
    float dvv = Dvec[d];
    float acc[TT];
    #pragma unroll
    for (int i = 0; i < TT; ++i) acc[i] = dvv;
    const float* ub   = u + (size_t)b * LSEQ * DMODEL + d;
    const float* kcol = kT + d;
    int mstart = t0 - 1024; if (mstart < 0) mstart = 0;
    int mend   = t0 + 1040; if (mend > LSEQ) mend = LSEQ;
    float kreg[31];
    {
        int jpb = mstart - t0 + 1024;
        #pragma unroll
        for (int r = 0; r < 31; ++r) kreg[r] = kcol[(jpb + r)*DMODEL];
    }
    for (int m0 = mstart; m0 < mend; m0 += TT) {
        float ureg[TT];
        #pragma unroll
        for (int mm = 0; mm < TT; ++mm) ureg[mm] = ub[(m0 + mm)*DMODEL];
        float knew[TT];
        if (m0 + TT < mend) {
            int jnb = m0 - t0 + 1024 + 31;
            #pragma unroll
            for (int r = 0; r < TT; ++r) knew[r] = kcol[(jnb + r)*DMODEL];
        } else {
            #pragma unroll
            for (int r = 0; r < TT; ++r) knew[r] = 0.f;
        }
        #pragma unroll
        for (int mm = 0; mm < TT; ++mm)
            #pragma unroll
            for (int tt = 0; tt < TT; ++tt)
                acc[tt] = fmaf(ureg[mm], kreg[mm - tt + 15], acc[tt]);
        #pragma unroll
        for (int r = 0; r < 15; ++r) kreg[r] = kreg[r + 16];
        #pragma unroll
        for (int r = 0; r < 16; ++r) kreg[15 + r] = knew[r];
    }
    float* ob = out + ((size_t)b * LSEQ + t0) * DMODEL + d;
    #pragma unroll
    for (int tt = 0; tt < TT; ++tt) ob[tt*DMODEL] = acc[tt];
}

// ============================================================ launch
extern "C" void kernel_launch(void* const* d_in, const int* in_sizes, int n_in,
                              void* d_out, int out_size, void* d_ws, size_t ws_size,
                              hipStream_t stream)
{
    const float* u  = (const float*)d_in[0];
    const float* Ar = (const float*)d_in[1];
    const float* Ai = (const float*)d_in[2];
    const float* Cr = (const float*)d_in[3];
    const float* Ci = (const float*)d_in[4];
    const float* Dv = (const float*)d_in[5];
    float* out = (float*)d_out;
    int B = in_sizes[0] / (LSEQ * DMODEL);

    if (B == 8) {
        s4d_fused<<<DMODEL, 512, 0, stream>>>(u, Ar, Ai, Cr, Ci, Dv, out);
    } else {
        float* kT = (float*)d_ws;
        s4d_build_k<<<DMODEL, 256, 0, stream>>>(Ar, Ai, Cr, Ci, kT);
        s4d_conv<<<dim3(LSEQ/TT, B), 256, 0, stream>>>(u, Dv, kT, out);
    }
}